// Round 13
// baseline (553.221 us; speedup 1.0000x reference)
//
#include <hip/hip_runtime.h>

// CustomGNN: 3x GAT layer (4 heads, 64 hid) + BN/ReLU (layers 0,1) + mean-pool + FC.
// All fp32. N=100000, E=500000, G=512.
// R13: k_gemm register double-buffer (prefetch chunk1 into VGPRs during chunk0
// compute -> hides ~500cy global latency). Everything else = R12 (best: 542us).

#define THREADS 256
#define LDP 36   // LDS row stride floats: conflict-free xs, 2-way ws
#define SFP 68   // sfold row stride

// ---- prep: fold[l][sd][head][k] = sum_c W[l][head*64+c][k] * att[l][head*64+c]
__global__ __launch_bounds__(THREADS) void k_prep(
    const float* __restrict__ Ws, const float* __restrict__ att_src,
    const float* __restrict__ att_dst, float* __restrict__ fold)
{
    int idx = blockIdx.x * THREADS + threadIdx.x;
    if (idx >= 3 * 2 * 4 * 64) return;
    int k = idx & 63, head = (idx >> 6) & 3, sd = (idx >> 8) & 1, l = idx >> 9;
    const float* att = (sd ? att_dst : att_src) + l * 256 + head * 64;
    const float* Wb  = Ws + (size_t)l * 16384 + (size_t)head * 64 * 64;
    float s = 0.f;
    #pragma unroll
    for (int c = 0; c < 64; ++c) s = fmaf(Wb[(size_t)c * 64 + k], att[c], s);
    fold[((l * 2 + sd) * 4 + head) * 64 + k] = s;
}

// ---- GEMM: h2 = x' @ W^T (head-interleaved cols) + fused a_s/a_d (gy==0) ----
// Register double-buffer: chunk k+1 global loads issue before chunk k compute.
__global__ __launch_bounds__(THREADS) void k_gemm(
    const float* __restrict__ x, const float* __restrict__ W,
    const float* __restrict__ fold_l,
    float* __restrict__ h, float* __restrict__ a_s, float* __restrict__ a_d, int n)
{
    __shared__ float xs[128][LDP];
    __shared__ float ws[128][LDP];
    __shared__ float sf[8 * SFP];
    const int tid  = threadIdx.x;
    const int tc   = tid & 15;
    const int tr   = tid >> 4;
    const int row0 = blockIdx.x * 128;
    const int col0 = blockIdx.y * 128;
    const bool gy0 = (blockIdx.y == 0);

    if (gy0) {
        #pragma unroll
        for (int j = 0; j < 2; ++j) {
            int idx = j * 256 + tid;
            sf[(idx >> 6) * SFP + (idx & 63)] = fold_l[idx];
        }
    }

    float acc[8][8];
    #pragma unroll
    for (int i = 0; i < 8; ++i)
        #pragma unroll
        for (int j = 0; j < 8; ++j) acc[i][j] = 0.f;
    float pa[4] = {0.f, 0.f, 0.f, 0.f};

    float4 xv[4], wv[4];
    // ---- load chunk 0 into regs, write to LDS ----
    #pragma unroll
    for (int i = 0; i < 4; ++i) {
        int f = i * 256 + tid, r = f >> 3, c4 = f & 7;
        int gr = row0 + r;
        xv[i] = make_float4(0.f, 0.f, 0.f, 0.f);
        if (gr < n) xv[i] = *(const float4*)(x + (size_t)gr * 64 + c4 * 4);
        int gp = col0 + r;
        int pr = (gp & 3) * 64 + (gp >> 2);     // head-interleave perm
        wv[i] = *(const float4*)(W + (size_t)pr * 64 + c4 * 4);
    }
    #pragma unroll
    for (int i = 0; i < 4; ++i) {
        int f = i * 256 + tid, r = f >> 3, c4 = f & 7;
        *(float4*)&xs[r][c4 * 4] = xv[i];
        *(float4*)&ws[r][c4 * 4] = wv[i];
    }
    __syncthreads();

    for (int ks2 = 0; ks2 < 2; ++ks2) {
        if (ks2 == 0) {
            // prefetch chunk 1 into regs; waitcnt lands after the compute loop
            #pragma unroll
            for (int i = 0; i < 4; ++i) {
                int f = i * 256 + tid, r = f >> 3, c4 = f & 7;
                int gr = row0 + r;
                xv[i] = make_float4(0.f, 0.f, 0.f, 0.f);
                if (gr < n) xv[i] = *(const float4*)(x + (size_t)gr * 64 + 32 + c4 * 4);
                int gp = col0 + r;
                int pr = (gp & 3) * 64 + (gp >> 2);
                wv[i] = *(const float4*)(W + (size_t)pr * 64 + 32 + c4 * 4);
            }
        }

        #pragma unroll 1   // CRITICAL: full unroll -> 256 VGPR + spill (R6 lesson)
        for (int ks = 0; ks < 8; ++ks) {
            float4 xr[8];
            #pragma unroll
            for (int i = 0; i < 8; ++i) xr[i] = *(const float4*)&xs[tr + 16 * i][ks * 4];
            #pragma unroll
            for (int j = 0; j < 8; ++j) {
                float4 w4 = *(const float4*)&ws[tc + 16 * j][ks * 4];
                #pragma unroll
                for (int i = 0; i < 8; ++i) {
                    acc[i][j] = fmaf(xr[i].x, w4.x, acc[i][j]);
                    acc[i][j] = fmaf(xr[i].y, w4.y, acc[i][j]);
                    acc[i][j] = fmaf(xr[i].z, w4.z, acc[i][j]);
                    acc[i][j] = fmaf(xr[i].w, w4.w, acc[i][j]);
                }
            }
        }
        // fused attention partial dots on this chunk (xs still valid)
        if (gy0) {
            const int vec = tid & 7;
            #pragma unroll
            for (int j = 0; j < 4; ++j) {
                int row = j * 32 + (tid >> 3);
                float s = 0.f;
                #pragma unroll
                for (int k = 0; k < 32; ++k)
                    s = fmaf(xs[row][k], sf[vec * SFP + ks2 * 32 + k], s);
                pa[j] += s;
            }
        }
        __syncthreads();
        if (ks2 == 0) {
            #pragma unroll
            for (int i = 0; i < 4; ++i) {
                int f = i * 256 + tid, r = f >> 3, c4 = f & 7;
                *(float4*)&xs[r][c4 * 4] = xv[i];
                *(float4*)&ws[r][c4 * 4] = wv[i];
            }
            __syncthreads();
        }
    }

    #pragma unroll
    for (int i = 0; i < 8; ++i) {
        int r = row0 + tr + 16 * i;
        if (r < n) {
            float* hp = h + (size_t)r * 256 + col0 + tc;
            #pragma unroll
            for (int j = 0; j < 8; ++j) hp[16 * j] = acc[i][j];
        }
    }
    if (gy0) {
        const int vec = tid & 7;
        #pragma unroll
        for (int j = 0; j < 4; ++j) {
            int rr = row0 + j * 32 + (tid >> 3);
            if (rr < n) {
                if (vec < 4) a_s[(size_t)rr * 4 + vec] = pa[j];
                else         a_d[(size_t)rr * 4 + (vec - 4)] = pa[j];
            }
        }
    }
}

// ---------------- counting sort of edges by destination --------------------
__global__ __launch_bounds__(THREADS) void k_hist(
    const int* __restrict__ col, int* __restrict__ hist, int E)
{
    int e = blockIdx.x * THREADS + threadIdx.x;
    if (e < E) atomicAdd(hist + col[e], 1);
}

__global__ __launch_bounds__(THREADS) void k_scan1(
    const int* __restrict__ hist, int* __restrict__ offs, int* __restrict__ partials, int n)
{
    __shared__ int buf0[256], buf1[256];
    int tid = threadIdx.x;
    int i = blockIdx.x * 256 + tid;
    int v = (i < n) ? hist[i] : 0;
    buf0[tid] = v;
    __syncthreads();
    int* src = buf0; int* dst = buf1;
    #pragma unroll
    for (int off = 1; off < 256; off <<= 1) {
        int t = src[tid];
        if (tid >= off) t += src[tid - off];
        dst[tid] = t;
        __syncthreads();
        int* tmp = src; src = dst; dst = tmp;
    }
    if (i < n) offs[i] = src[tid] - v;
    if (tid == 255) partials[blockIdx.x] = src[255];
}

__global__ __launch_bounds__(512) void k_scan2(int* __restrict__ partials, int nb)
{
    __shared__ int buf0[512], buf1[512];
    int tid = threadIdx.x;
    int v = (tid < nb) ? partials[tid] : 0;
    buf0[tid] = v;
    __syncthreads();
    int* src = buf0; int* dst = buf1;
    #pragma unroll
    for (int off = 1; off < 512; off <<= 1) {
        int t = src[tid];
        if (tid >= off) t += src[tid - off];
        dst[tid] = t;
        __syncthreads();
        int* tmp = src; src = dst; dst = tmp;
    }
    if (tid < nb) partials[tid] = src[tid] - v;
}

__global__ __launch_bounds__(THREADS) void k_scan3(
    int* __restrict__ offs, const int* __restrict__ partials, int n)
{
    int i = blockIdx.x * THREADS + threadIdx.x;
    if (i < n) offs[i] += partials[i >> 8];
}

__global__ __launch_bounds__(THREADS) void k_scatter(
    const int* __restrict__ row, const int* __restrict__ col,
    const int* __restrict__ offs, int* __restrict__ tmpc,
    int* __restrict__ rs, int E)
{
    int e = blockIdx.x * THREADS + threadIdx.x;
    if (e >= E) return;
    int c = col[e];
    int pos = offs[c] + atomicAdd(tmpc + c, 1);
    rs[pos] = row[e];
}

// ---- fused gather aggregation: score+exp+weighted-sum+psum in one pass ----
__global__ __launch_bounds__(THREADS) void k_gat(
    const int* __restrict__ rs, const int* __restrict__ offs, const int* __restrict__ deg,
    const float* __restrict__ a_s, const float* __restrict__ a_d,
    const float* __restrict__ h,
    const float* __restrict__ bng, const float* __restrict__ bnb,
    const float* __restrict__ bnm, const float* __restrict__ bnv, int use_bn,
    float* __restrict__ out, int n)
{
    int wid  = (blockIdx.x * THREADS + threadIdx.x) >> 6;
    int lane = threadIdx.x & 63;
    if (wid >= n) return;
    const int start = offs[wid];
    const int d     = deg[wid];
    const float4 ad = *(const float4*)(a_d + (size_t)wid * 4);

    float acc0 = 0.f, acc1 = 0.f, acc2 = 0.f, acc3 = 0.f;
    float ps0 = 0.f, ps1 = 0.f, ps2 = 0.f, ps3 = 0.f;
    for (int i = 0; i < d; ++i) {
        int r = rs[start + i];
        float4 as = *(const float4*)(a_s + (size_t)r * 4);
        float4 v  = *(const float4*)(h + (size_t)r * 256 + lane * 4);
        float v0 = as.x + ad.x, v1 = as.y + ad.y, v2 = as.z + ad.z, v3 = as.w + ad.w;
        v0 = v0 >= 0.f ? v0 : 0.2f * v0;
        v1 = v1 >= 0.f ? v1 : 0.2f * v1;
        v2 = v2 >= 0.f ? v2 : 0.2f * v2;
        v3 = v3 >= 0.f ? v3 : 0.2f * v3;
        float p0 = __expf(v0), p1 = __expf(v1), p2 = __expf(v2), p3 = __expf(v3);
        ps0 += p0; ps1 += p1; ps2 += p2; ps3 += p3;
        acc0 = fmaf(p0, v.x, acc0);
        acc1 = fmaf(p1, v.y, acc1);
        acc2 = fmaf(p2, v.z, acc2);
        acc3 = fmaf(p3, v.w, acc3);
    }
    float acc = acc0 * (0.25f / (ps0 + 1e-8f)) + acc1 * (0.25f / (ps1 + 1e-8f))
              + acc2 * (0.25f / (ps2 + 1e-8f)) + acc3 * (0.25f / (ps3 + 1e-8f));
    if (use_bn) {
        float scale = bng[lane] * rsqrtf(bnv[lane] + 1e-5f);
        float shift = bnb[lane] - bnm[lane] * scale;
        acc = fmaxf(fmaf(acc, scale, shift), 0.f);
    }
    out[(size_t)wid * 64 + lane] = acc;
}

// ---- segmented mean pool (batch sorted) ----
#define POOL_CHUNK 32
__global__ __launch_bounds__(THREADS) void k_pool(
    const float* __restrict__ xf, const int* __restrict__ batch,
    float* __restrict__ sums, float* __restrict__ cnt, int n)
{
    int wid  = (blockIdx.x * THREADS + threadIdx.x) >> 6;
    int lane = threadIdx.x & 63;
    int n0 = wid * POOL_CHUNK;
    if (n0 >= n) return;
    int n1 = min(n0 + POOL_CHUNK, n);
    int g = batch[n0];
    float acc = 0.f, c = 0.f;
    for (int i = n0; i < n1; ++i) {
        int gi = batch[i];
        if (gi != g) {
            atomicAdd(sums + (size_t)g * 64 + lane, acc);
            if (lane == 0) atomicAdd(cnt + g, c);
            g = gi; acc = 0.f; c = 0.f;
        }
        acc += xf[(size_t)i * 64 + lane];
        c += 1.f;
    }
    atomicAdd(sums + (size_t)g * 64 + lane, acc);
    if (lane == 0) atomicAdd(cnt + g, c);
}

__global__ __launch_bounds__(THREADS) void k_fc(
    const float* __restrict__ sums, const float* __restrict__ cnt,
    const float* __restrict__ fw, const float* __restrict__ fb,
    float* __restrict__ out, int G)
{
    int g = blockIdx.x * THREADS + threadIdx.x;
    if (g >= G) return;
    float cdiv = fmaxf(cnt[g], 1.f);
    float o0 = fb[0], o1 = fb[1];
    for (int k = 0; k < 64; ++k) {
        float p = sums[(size_t)g * 64 + k] / cdiv;
        o0 = fmaf(p, fw[k], o0);
        o1 = fmaf(p, fw[64 + k], o1);
    }
    out[(size_t)g * 2 + 0] = o0;
    out[(size_t)g * 2 + 1] = o1;
}

static inline size_t align256(size_t x) { return (x + 255) & ~(size_t)255; }

extern "C" void kernel_launch(void* const* d_in, const int* in_sizes, int n_in,
                              void* d_out, int out_size, void* d_ws, size_t ws_size,
                              hipStream_t stream)
{
    const float* x        = (const float*)d_in[0];
    const int*   eidx     = (const int*)d_in[1];
    const int*   batch    = (const int*)d_in[2];
    const float* Ws       = (const float*)d_in[3];
    const float* att_src  = (const float*)d_in[4];
    const float* att_dst  = (const float*)d_in[5];
    const float* bn_gamma = (const float*)d_in[6];
    const float* bn_beta  = (const float*)d_in[7];
    const float* bn_mean  = (const float*)d_in[8];
    const float* bn_var   = (const float*)d_in[9];
    const float* fc_w     = (const float*)d_in[10];
    const float* fc_b     = (const float*)d_in[11];

    const int N = in_sizes[0] / 64;
    const int E = in_sizes[1] / 2;
    const int G = 512;
    const int* row = eidx;
    const int* col = eidx + E;

    char* p = (char*)d_ws;
    float* h     = (float*)p; p += align256((size_t)N * 256 * 4);
    float* a_s   = (float*)p; p += align256((size_t)N * 4 * 4);
    float* a_d   = (float*)p; p += align256((size_t)N * 4 * 4);
    float* xb0   = (float*)p; p += align256((size_t)N * 64 * 4);
    float* xb1   = (float*)p; p += align256((size_t)N * 64 * 4);
    int*   hist  = (int*)p;   p += align256((size_t)N * 4);
    int*   offs  = (int*)p;   p += align256((size_t)N * 4);
    int*   tmpc  = (int*)p;   p += align256((size_t)N * 4);
    int*   part  = (int*)p;   p += align256((size_t)1024 * 4);
    int*   rs    = (int*)p;   p += align256((size_t)E * 4);
    float* fold  = (float*)p; p += align256((size_t)1536 * 4);
    float* sums  = (float*)p; p += align256((size_t)G * 64 * 4);
    float* cnt   = (float*)p; p += align256((size_t)G * 4);
    (void)ws_size; (void)n_in; (void)out_size;

    const int nb = (N + 255) / 256;
    const int eb = (E + THREADS - 1) / THREADS;

    // ---- prep folded attention vectors + CSR by destination ----
    k_prep<<<6, THREADS, 0, stream>>>(Ws, att_src, att_dst, fold);
    hipMemsetAsync(hist, 0, (size_t)N * 4, stream);
    hipMemsetAsync(tmpc, 0, (size_t)N * 4, stream);
    k_hist<<<eb, THREADS, 0, stream>>>(col, hist, E);
    k_scan1<<<nb, THREADS, 0, stream>>>(hist, offs, part, N);
    k_scan2<<<1, 512, 0, stream>>>(part, nb);
    k_scan3<<<nb, THREADS, 0, stream>>>(offs, part, N);
    k_scatter<<<eb, THREADS, 0, stream>>>(row, col, offs, tmpc, rs, E);

    // ---- 3 GAT layers ----
    const float* xin = x;
    for (int l = 0; l < 3; ++l) {
        float* xout = (l == 1) ? xb1 : xb0;
        dim3 ggrid((N + 127) / 128, 2);
        k_gemm<<<ggrid, THREADS, 0, stream>>>(
            xin, Ws + (size_t)l * 16384, fold + (size_t)l * 512, h, a_s, a_d, N);
        k_gat<<<((size_t)N * 64 + THREADS - 1) / THREADS, THREADS, 0, stream>>>(
            rs, offs, hist, a_s, a_d, h,
            bn_gamma + l * 64, bn_beta + l * 64, bn_mean + l * 64, bn_var + l * 64,
            (l < 2) ? 1 : 0, xout, N);
        xin = xout;
    }

    // ---- pool + fc ----
    hipMemsetAsync(sums, 0, (size_t)G * 64 * 4, stream);
    hipMemsetAsync(cnt, 0, (size_t)G * 4, stream);
    int pool_waves = (N + POOL_CHUNK - 1) / POOL_CHUNK;
    k_pool<<<((size_t)pool_waves * 64 + THREADS - 1) / THREADS, THREADS, 0, stream>>>(
        xin, batch, sums, cnt, N);
    k_fc<<<(G + THREADS - 1) / THREADS, THREADS, 0, stream>>>(
        sums, cnt, fc_w, fc_b, (float*)d_out, G);
}

// Round 14
// 541.749 us; speedup vs baseline: 1.0212x; 1.0212x over previous
//
#include <hip/hip_runtime.h>

// CustomGNN: 3x GAT layer (4 heads, 64 hid) + BN/ReLU (layers 0,1) + mean-pool + FC.
// All fp32. N=100000, E=500000, G=512.
// R14 = R12 verbatim (best: 542us; R13's register dbuf regressed to 553).
// k_gat is at the random-gather fetch floor (273MB @ 3.35TB/s, 6 variants same
// rate); score+exp fused into k_gat; attention projections fused into k_gemm.

#define THREADS 256
#define LDP 36   // LDS row stride floats: conflict-free xs, 2-way ws
#define SFP 68   // sfold row stride

// ---- prep: fold[l][sd][head][k] = sum_c W[l][head*64+c][k] * att[l][head*64+c]
__global__ __launch_bounds__(THREADS) void k_prep(
    const float* __restrict__ Ws, const float* __restrict__ att_src,
    const float* __restrict__ att_dst, float* __restrict__ fold)
{
    int idx = blockIdx.x * THREADS + threadIdx.x;
    if (idx >= 3 * 2 * 4 * 64) return;
    int k = idx & 63, head = (idx >> 6) & 3, sd = (idx >> 8) & 1, l = idx >> 9;
    const float* att = (sd ? att_dst : att_src) + l * 256 + head * 64;
    const float* Wb  = Ws + (size_t)l * 16384 + (size_t)head * 64 * 64;
    float s = 0.f;
    #pragma unroll
    for (int c = 0; c < 64; ++c) s = fmaf(Wb[(size_t)c * 64 + k], att[c], s);
    fold[((l * 2 + sd) * 4 + head) * 64 + k] = s;
}

// ---- GEMM: h2 = x' @ W^T (head-interleaved cols) + fused a_s/a_d (gy==0) ----
__global__ __launch_bounds__(THREADS) void k_gemm(
    const float* __restrict__ x, const float* __restrict__ W,
    const float* __restrict__ fold_l,
    float* __restrict__ h, float* __restrict__ a_s, float* __restrict__ a_d, int n)
{
    __shared__ float xs[128][LDP];
    __shared__ float ws[128][LDP];
    __shared__ float sf[8 * SFP];
    const int tid  = threadIdx.x;
    const int tc   = tid & 15;
    const int tr   = tid >> 4;
    const int row0 = blockIdx.x * 128;
    const int col0 = blockIdx.y * 128;
    const bool gy0 = (blockIdx.y == 0);

    if (gy0) {
        #pragma unroll
        for (int j = 0; j < 2; ++j) {
            int idx = j * 256 + tid;
            sf[(idx >> 6) * SFP + (idx & 63)] = fold_l[idx];
        }
    }

    float acc[8][8];
    #pragma unroll
    for (int i = 0; i < 8; ++i)
        #pragma unroll
        for (int j = 0; j < 8; ++j) acc[i][j] = 0.f;
    float pa[4] = {0.f, 0.f, 0.f, 0.f};

    for (int ks2 = 0; ks2 < 2; ++ks2) {
        #pragma unroll
        for (int i = 0; i < 4; ++i) {
            int flat4 = i * 256 + tid;
            int r  = flat4 >> 3;
            int c4 = flat4 & 7;
            int gr = row0 + r;
            float4 v = make_float4(0.f, 0.f, 0.f, 0.f);
            if (gr < n) v = *(const float4*)(x + (size_t)gr * 64 + ks2 * 32 + c4 * 4);
            *(float4*)&xs[r][c4 * 4] = v;
            int gp = col0 + r;                  // output position
            int pr = (gp & 3) * 64 + (gp >> 2); // original W row (head-interleave perm)
            float4 wv = *(const float4*)(W + (size_t)pr * 64 + ks2 * 32 + c4 * 4);
            *(float4*)&ws[r][c4 * 4] = wv;
        }
        __syncthreads();

        #pragma unroll 1   // CRITICAL: full unroll -> 256 VGPR + spill (R6 lesson)
        for (int ks = 0; ks < 8; ++ks) {
            float4 xr[8];
            #pragma unroll
            for (int i = 0; i < 8; ++i) xr[i] = *(const float4*)&xs[tr + 16 * i][ks * 4];
            #pragma unroll
            for (int j = 0; j < 8; ++j) {
                float4 w4 = *(const float4*)&ws[tc + 16 * j][ks * 4];
                #pragma unroll
                for (int i = 0; i < 8; ++i) {
                    acc[i][j] = fmaf(xr[i].x, w4.x, acc[i][j]);
                    acc[i][j] = fmaf(xr[i].y, w4.y, acc[i][j]);
                    acc[i][j] = fmaf(xr[i].z, w4.z, acc[i][j]);
                    acc[i][j] = fmaf(xr[i].w, w4.w, acc[i][j]);
                }
            }
        }
        // fused attention partial dots on this 32-k chunk (xs still valid)
        if (gy0) {
            const int vec = tid & 7;
            #pragma unroll
            for (int j = 0; j < 4; ++j) {
                int row = j * 32 + (tid >> 3);
                float s = 0.f;
                #pragma unroll
                for (int k = 0; k < 32; ++k)
                    s = fmaf(xs[row][k], sf[vec * SFP + ks2 * 32 + k], s);
                pa[j] += s;
            }
        }
        __syncthreads();
    }

    #pragma unroll
    for (int i = 0; i < 8; ++i) {
        int r = row0 + tr + 16 * i;
        if (r < n) {
            float* hp = h + (size_t)r * 256 + col0 + tc;
            #pragma unroll
            for (int j = 0; j < 8; ++j) hp[16 * j] = acc[i][j];
        }
    }
    if (gy0) {
        const int vec = tid & 7;
        #pragma unroll
        for (int j = 0; j < 4; ++j) {
            int rr = row0 + j * 32 + (tid >> 3);
            if (rr < n) {
                if (vec < 4) a_s[(size_t)rr * 4 + vec] = pa[j];
                else         a_d[(size_t)rr * 4 + (vec - 4)] = pa[j];
            }
        }
    }
}

// ---------------- counting sort of edges by destination --------------------
__global__ __launch_bounds__(THREADS) void k_hist(
    const int* __restrict__ col, int* __restrict__ hist, int E)
{
    int e = blockIdx.x * THREADS + threadIdx.x;
    if (e < E) atomicAdd(hist + col[e], 1);
}

__global__ __launch_bounds__(THREADS) void k_scan1(
    const int* __restrict__ hist, int* __restrict__ offs, int* __restrict__ partials, int n)
{
    __shared__ int buf0[256], buf1[256];
    int tid = threadIdx.x;
    int i = blockIdx.x * 256 + tid;
    int v = (i < n) ? hist[i] : 0;
    buf0[tid] = v;
    __syncthreads();
    int* src = buf0; int* dst = buf1;
    #pragma unroll
    for (int off = 1; off < 256; off <<= 1) {
        int t = src[tid];
        if (tid >= off) t += src[tid - off];
        dst[tid] = t;
        __syncthreads();
        int* tmp = src; src = dst; dst = tmp;
    }
    if (i < n) offs[i] = src[tid] - v;
    if (tid == 255) partials[blockIdx.x] = src[255];
}

__global__ __launch_bounds__(512) void k_scan2(int* __restrict__ partials, int nb)
{
    __shared__ int buf0[512], buf1[512];
    int tid = threadIdx.x;
    int v = (tid < nb) ? partials[tid] : 0;
    buf0[tid] = v;
    __syncthreads();
    int* src = buf0; int* dst = buf1;
    #pragma unroll
    for (int off = 1; off < 512; off <<= 1) {
        int t = src[tid];
        if (tid >= off) t += src[tid - off];
        dst[tid] = t;
        __syncthreads();
        int* tmp = src; src = dst; dst = tmp;
    }
    if (tid < nb) partials[tid] = src[tid] - v;
}

__global__ __launch_bounds__(THREADS) void k_scan3(
    int* __restrict__ offs, const int* __restrict__ partials, int n)
{
    int i = blockIdx.x * THREADS + threadIdx.x;
    if (i < n) offs[i] += partials[i >> 8];
}

__global__ __launch_bounds__(THREADS) void k_scatter(
    const int* __restrict__ row, const int* __restrict__ col,
    const int* __restrict__ offs, int* __restrict__ tmpc,
    int* __restrict__ rs, int E)
{
    int e = blockIdx.x * THREADS + threadIdx.x;
    if (e >= E) return;
    int c = col[e];
    int pos = offs[c] + atomicAdd(tmpc + c, 1);
    rs[pos] = row[e];
}

// ---- fused gather aggregation: score+exp+weighted-sum+psum in one pass ----
__global__ __launch_bounds__(THREADS) void k_gat(
    const int* __restrict__ rs, const int* __restrict__ offs, const int* __restrict__ deg,
    const float* __restrict__ a_s, const float* __restrict__ a_d,
    const float* __restrict__ h,
    const float* __restrict__ bng, const float* __restrict__ bnb,
    const float* __restrict__ bnm, const float* __restrict__ bnv, int use_bn,
    float* __restrict__ out, int n)
{
    int wid  = (blockIdx.x * THREADS + threadIdx.x) >> 6;
    int lane = threadIdx.x & 63;
    if (wid >= n) return;
    const int start = offs[wid];
    const int d     = deg[wid];
    const float4 ad = *(const float4*)(a_d + (size_t)wid * 4);

    float acc0 = 0.f, acc1 = 0.f, acc2 = 0.f, acc3 = 0.f;
    float ps0 = 0.f, ps1 = 0.f, ps2 = 0.f, ps3 = 0.f;
    for (int i = 0; i < d; ++i) {
        int r = rs[start + i];
        float4 as = *(const float4*)(a_s + (size_t)r * 4);
        float4 v  = *(const float4*)(h + (size_t)r * 256 + lane * 4);
        float v0 = as.x + ad.x, v1 = as.y + ad.y, v2 = as.z + ad.z, v3 = as.w + ad.w;
        v0 = v0 >= 0.f ? v0 : 0.2f * v0;
        v1 = v1 >= 0.f ? v1 : 0.2f * v1;
        v2 = v2 >= 0.f ? v2 : 0.2f * v2;
        v3 = v3 >= 0.f ? v3 : 0.2f * v3;
        float p0 = __expf(v0), p1 = __expf(v1), p2 = __expf(v2), p3 = __expf(v3);
        ps0 += p0; ps1 += p1; ps2 += p2; ps3 += p3;
        acc0 = fmaf(p0, v.x, acc0);
        acc1 = fmaf(p1, v.y, acc1);
        acc2 = fmaf(p2, v.z, acc2);
        acc3 = fmaf(p3, v.w, acc3);
    }
    float acc = acc0 * (0.25f / (ps0 + 1e-8f)) + acc1 * (0.25f / (ps1 + 1e-8f))
              + acc2 * (0.25f / (ps2 + 1e-8f)) + acc3 * (0.25f / (ps3 + 1e-8f));
    if (use_bn) {
        float scale = bng[lane] * rsqrtf(bnv[lane] + 1e-5f);
        float shift = bnb[lane] - bnm[lane] * scale;
        acc = fmaxf(fmaf(acc, scale, shift), 0.f);
    }
    out[(size_t)wid * 64 + lane] = acc;
}

// ---- segmented mean pool (batch sorted) ----
#define POOL_CHUNK 32
__global__ __launch_bounds__(THREADS) void k_pool(
    const float* __restrict__ xf, const int* __restrict__ batch,
    float* __restrict__ sums, float* __restrict__ cnt, int n)
{
    int wid  = (blockIdx.x * THREADS + threadIdx.x) >> 6;
    int lane = threadIdx.x & 63;
    int n0 = wid * POOL_CHUNK;
    if (n0 >= n) return;
    int n1 = min(n0 + POOL_CHUNK, n);
    int g = batch[n0];
    float acc = 0.f, c = 0.f;
    for (int i = n0; i < n1; ++i) {
        int gi = batch[i];
        if (gi != g) {
            atomicAdd(sums + (size_t)g * 64 + lane, acc);
            if (lane == 0) atomicAdd(cnt + g, c);
            g = gi; acc = 0.f; c = 0.f;
        }
        acc += xf[(size_t)i * 64 + lane];
        c += 1.f;
    }
    atomicAdd(sums + (size_t)g * 64 + lane, acc);
    if (lane == 0) atomicAdd(cnt + g, c);
}

__global__ __launch_bounds__(THREADS) void k_fc(
    const float* __restrict__ sums, const float* __restrict__ cnt,
    const float* __restrict__ fw, const float* __restrict__ fb,
    float* __restrict__ out, int G)
{
    int g = blockIdx.x * THREADS + threadIdx.x;
    if (g >= G) return;
    float cdiv = fmaxf(cnt[g], 1.f);
    float o0 = fb[0], o1 = fb[1];
    for (int k = 0; k < 64; ++k) {
        float p = sums[(size_t)g * 64 + k] / cdiv;
        o0 = fmaf(p, fw[k], o0);
        o1 = fmaf(p, fw[64 + k], o1);
    }
    out[(size_t)g * 2 + 0] = o0;
    out[(size_t)g * 2 + 1] = o1;
}

static inline size_t align256(size_t x) { return (x + 255) & ~(size_t)255; }

extern "C" void kernel_launch(void* const* d_in, const int* in_sizes, int n_in,
                              void* d_out, int out_size, void* d_ws, size_t ws_size,
                              hipStream_t stream)
{
    const float* x        = (const float*)d_in[0];
    const int*   eidx     = (const int*)d_in[1];
    const int*   batch    = (const int*)d_in[2];
    const float* Ws       = (const float*)d_in[3];
    const float* att_src  = (const float*)d_in[4];
    const float* att_dst  = (const float*)d_in[5];
    const float* bn_gamma = (const float*)d_in[6];
    const float* bn_beta  = (const float*)d_in[7];
    const float* bn_mean  = (const float*)d_in[8];
    const float* bn_var   = (const float*)d_in[9];
    const float* fc_w     = (const float*)d_in[10];
    const float* fc_b     = (const float*)d_in[11];

    const int N = in_sizes[0] / 64;
    const int E = in_sizes[1] / 2;
    const int G = 512;
    const int* row = eidx;
    const int* col = eidx + E;

    char* p = (char*)d_ws;
    float* h     = (float*)p; p += align256((size_t)N * 256 * 4);
    float* a_s   = (float*)p; p += align256((size_t)N * 4 * 4);
    float* a_d   = (float*)p; p += align256((size_t)N * 4 * 4);
    float* xb0   = (float*)p; p += align256((size_t)N * 64 * 4);
    float* xb1   = (float*)p; p += align256((size_t)N * 64 * 4);
    int*   hist  = (int*)p;   p += align256((size_t)N * 4);
    int*   offs  = (int*)p;   p += align256((size_t)N * 4);
    int*   tmpc  = (int*)p;   p += align256((size_t)N * 4);
    int*   part  = (int*)p;   p += align256((size_t)1024 * 4);
    int*   rs    = (int*)p;   p += align256((size_t)E * 4);
    float* fold  = (float*)p; p += align256((size_t)1536 * 4);
    float* sums  = (float*)p; p += align256((size_t)G * 64 * 4);
    float* cnt   = (float*)p; p += align256((size_t)G * 4);
    (void)ws_size; (void)n_in; (void)out_size;

    const int nb = (N + 255) / 256;
    const int eb = (E + THREADS - 1) / THREADS;

    // ---- prep folded attention vectors + CSR by destination ----
    k_prep<<<6, THREADS, 0, stream>>>(Ws, att_src, att_dst, fold);
    hipMemsetAsync(hist, 0, (size_t)N * 4, stream);
    hipMemsetAsync(tmpc, 0, (size_t)N * 4, stream);
    k_hist<<<eb, THREADS, 0, stream>>>(col, hist, E);
    k_scan1<<<nb, THREADS, 0, stream>>>(hist, offs, part, N);
    k_scan2<<<1, 512, 0, stream>>>(part, nb);
    k_scan3<<<nb, THREADS, 0, stream>>>(offs, part, N);
    k_scatter<<<eb, THREADS, 0, stream>>>(row, col, offs, tmpc, rs, E);

    // ---- 3 GAT layers ----
    const float* xin = x;
    for (int l = 0; l < 3; ++l) {
        float* xout = (l == 1) ? xb1 : xb0;
        dim3 ggrid((N + 127) / 128, 2);
        k_gemm<<<ggrid, THREADS, 0, stream>>>(
            xin, Ws + (size_t)l * 16384, fold + (size_t)l * 512, h, a_s, a_d, N);
        k_gat<<<((size_t)N * 64 + THREADS - 1) / THREADS, THREADS, 0, stream>>>(
            rs, offs, hist, a_s, a_d, h,
            bn_gamma + l * 64, bn_beta + l * 64, bn_mean + l * 64, bn_var + l * 64,
            (l < 2) ? 1 : 0, xout, N);
        xin = xout;
    }

    // ---- pool + fc ----
    hipMemsetAsync(sums, 0, (size_t)G * 64 * 4, stream);
    hipMemsetAsync(cnt, 0, (size_t)G * 4, stream);
    int pool_waves = (N + POOL_CHUNK - 1) / POOL_CHUNK;
    k_pool<<<((size_t)pool_waves * 64 + THREADS - 1) / THREADS, THREADS, 0, stream>>>(
        xin, batch, sums, cnt, N);
    k_fc<<<(G + THREADS - 1) / THREADS, THREADS, 0, stream>>>(
        sums, cnt, fc_w, fc_b, (float*)d_out, G);
}